// Round 3
// baseline (255.840 us; speedup 1.0000x reference)
//
#include <hip/hip_runtime.h>

using f32x4 = __attribute__((ext_vector_type(4))) float;
using f32x2 = __attribute__((ext_vector_type(2))) float;
using s16x8 = __attribute__((ext_vector_type(8))) short;
using u16x4 = __attribute__((ext_vector_type(4))) unsigned short;
using i32x4 = __attribute__((ext_vector_type(4))) int;

#define BB 8
#define NPTS 8192
#define SS 2048
#define D1C 64
#define D2C 256
#define C0K 320
#define MM 65536
#define SCHUNKS 8
#define SCH (SS / SCHUNKS)  // 256

__device__ __forceinline__ float b2f(unsigned short h) {
  unsigned int u = ((unsigned int)h) << 16;
  return __builtin_bit_cast(float, u);
}
__device__ __forceinline__ unsigned short f2b(float f) {
  unsigned int u = __builtin_bit_cast(unsigned int, f);
  u += 0x7fffu + ((u >> 16) & 1u);
  return (unsigned short)(u >> 16);
}

// top-3 insert: distances via med3/min (3 VALU), indices via cmp+cndmask (strict < => stable)
__device__ __forceinline__ void ins3(float& dd0, float& dd1, float& dd2, int& ii0, int& ii1,
                                     int& ii2, float d, int s) {
  bool c0 = d < dd0, c1 = d < dd1, c2 = d < dd2;
  ii2 = c1 ? ii1 : (c2 ? s : ii2);
  ii1 = c0 ? ii0 : (c1 ? s : ii1);
  ii0 = c0 ? s : ii0;
  dd2 = __builtin_amdgcn_fmed3f(dd1, dd2, d);
  dd1 = __builtin_amdgcn_fmed3f(dd0, dd1, d);
  dd0 = fminf(dd0, d);
}

// ---------------- cast fp32 weights -> bf16 ----------------
__global__ __launch_bounds__(256) void k_castw(const float* __restrict__ src,
                                               unsigned short* __restrict__ dst, int n) {
  int i4 = (blockIdx.x * 256 + threadIdx.x) * 4;
  if (i4 >= n) return;
  f32x4 v = *(const f32x4*)(src + i4);
  u16x4 o;
#pragma unroll
  for (int j = 0; j < 4; ++j) o[j] = f2b(v[j]);
  *(u16x4*)(dst + i4) = o;
}

// ---------------- transpose points2 [B][256][S] -> f2t [B][S][256] ----------------
__global__ __launch_bounds__(256) void k_tr_f2t(const float* __restrict__ pts2,
                                                float* __restrict__ f2t) {
  __shared__ float tile[64 * 65];
  const int t = threadIdx.x;
  const int s0 = blockIdx.x * 64, c0 = blockIdx.y * 64, b = blockIdx.z;
#pragma unroll
  for (int i = 0; i < 4; ++i) {
    const int cl = i * 16 + (t >> 4);
    const int s4 = (t & 15) * 4;
    f32x4 v = *(const f32x4*)(pts2 + ((size_t)(b * D2C + c0 + cl)) * SS + s0 + s4);
#pragma unroll
    for (int j = 0; j < 4; ++j) tile[cl * 65 + s4 + j] = v[j];
  }
  __syncthreads();
#pragma unroll
  for (int i = 0; i < 4; ++i) {
    const int sl = i * 16 + (t >> 4);
    const int c4 = (t & 15) * 4;
    f32x4 o;
#pragma unroll
    for (int j = 0; j < 4; ++j) o[j] = tile[(c4 + j) * 65 + sl];
    *(f32x4*)(f2t + ((size_t)(b * SS + s0 + sl)) * D2C + c0 + c4) = o;
  }
}

// ---------------- transpose points1 [B][64][N] -> X0 cols 0..63 (bf16) ----------------
__global__ __launch_bounds__(256) void k_tr_x0(const float* __restrict__ pts1,
                                               unsigned short* __restrict__ X0) {
  __shared__ float tile[64 * 65];
  const int t = threadIdx.x;
  const int n0 = blockIdx.x * 64, b = blockIdx.y;
#pragma unroll
  for (int i = 0; i < 4; ++i) {
    const int cl = i * 16 + (t >> 4);
    const int n4 = (t & 15) * 4;
    f32x4 v = *(const f32x4*)(pts1 + ((size_t)(b * D1C + cl)) * NPTS + n0 + n4);
#pragma unroll
    for (int j = 0; j < 4; ++j) tile[cl * 65 + n4 + j] = v[j];
  }
  __syncthreads();
#pragma unroll
  for (int i = 0; i < 4; ++i) {
    const int nl = i * 16 + (t >> 4);
    const int c4 = (t & 15) * 4;
    u16x4 o;
#pragma unroll
    for (int j = 0; j < 4; ++j) o[j] = f2b(tile[(c4 + j) * 65 + nl]);
    *(u16x4*)(X0 + ((size_t)(b * NPTS + n0 + nl)) * C0K + c4) = o;
  }
}

// ---------------- 3-NN partial: per S-chunk top-3, 4 query pts/thread ----------------
// comparison key d' = |p2|^2 - 2<p1,p2>  (drop |p1|^2: constant per query, monotone)
__global__ __launch_bounds__(256) void k_dist(const float* __restrict__ xyz1,
                                              const float* __restrict__ xyz2,
                                              f32x4* __restrict__ pd,
                                              i32x4* __restrict__ pi) {
  __shared__ f32x4 p2[SCH];
  const int t = threadIdx.x;
  const int b = blockIdx.z, cy = blockIdx.y, ss0 = cy * SCH;
  const float* xz2 = xyz2 + (size_t)b * 3 * SS;
  {
    const int s = t;
    float x = xz2[ss0 + s], y = xz2[SS + ss0 + s], z = xz2[2 * SS + ss0 + s];
    f32x4 q;
    q[0] = x; q[1] = y; q[2] = z; q[3] = x * x + y * y + z * z;
    p2[s] = q;
  }
  __syncthreads();
  const float* xz1 = xyz1 + (size_t)b * 3 * NPTS;
  const int nb = blockIdx.x * 1024 + t;
  float tx[4], ty[4], tz[4], d0[4], d1[4], d2[4];
  int i0[4], i1[4], i2[4];
#pragma unroll
  for (int j = 0; j < 4; ++j) {
    const int n = nb + j * 256;
    tx[j] = -2.f * xz1[n];
    ty[j] = -2.f * xz1[NPTS + n];
    tz[j] = -2.f * xz1[2 * NPTS + n];
    d0[j] = d1[j] = d2[j] = 1e30f;
    i0[j] = i1[j] = i2[j] = 0;
  }
#pragma unroll 4
  for (int s = 0; s < SCH; ++s) {
    const f32x4 q = p2[s];
    const int sg = ss0 + s;
#pragma unroll
    for (int j = 0; j < 4; ++j) {
      float d = fmaf(tx[j], q[0], fmaf(ty[j], q[1], fmaf(tz[j], q[2], q[3])));
      ins3(d0[j], d1[j], d2[j], i0[j], i1[j], i2[j], d, sg);
    }
  }
#pragma unroll
  for (int j = 0; j < 4; ++j) {
    const int n = nb + j * 256;
    const float r1 = 0.25f * (tx[j] * tx[j] + ty[j] * ty[j] + tz[j] * tz[j]);
    const size_t p = ((size_t)(b * SCHUNKS + cy)) * NPTS + n;
    f32x4 dv;
    dv[0] = d0[j]; dv[1] = d1[j]; dv[2] = d2[j]; dv[3] = r1;
    i32x4 iv;
    iv[0] = i0[j]; iv[1] = i1[j]; iv[2] = i2[j]; iv[3] = 0;
    pd[p] = dv;
    pi[p] = iv;
  }
}

// ---------------- merge partial top-3 -> final idx + weights ----------------
__global__ __launch_bounds__(256) void k_merge(const f32x4* __restrict__ pd,
                                               const i32x4* __restrict__ pi,
                                               int* __restrict__ idxb,
                                               float* __restrict__ wb) {
  const int p = blockIdx.x * 256 + threadIdx.x;
  const int b = p >> 13, n = p & 8191;
  const size_t base = ((size_t)(b * SCHUNKS)) * NPTS + n;
  f32x4 dv = pd[base];
  i32x4 ivv = pi[base];
  const float r1 = dv[3];
  float d0 = dv[0], d1 = dv[1], d2 = dv[2];
  int i0 = ivv[0], i1 = ivv[1], i2 = ivv[2];
#pragma unroll
  for (int c = 1; c < SCHUNKS; ++c) {
    f32x4 dc = pd[base + (size_t)c * NPTS];
    i32x4 ic = pi[base + (size_t)c * NPTS];
    ins3(d0, d1, d2, i0, i1, i2, dc[0], ic[0]);
    ins3(d0, d1, d2, i0, i1, i2, dc[1], ic[1]);
    ins3(d0, d1, d2, i0, i1, i2, dc[2], ic[2]);
  }
  float w0 = 1.f / (d0 + r1 + 1e-8f), w1 = 1.f / (d1 + r1 + 1e-8f), w2 = 1.f / (d2 + r1 + 1e-8f);
  float inv = 1.f / (w0 + w1 + w2);
  i32x4 iv;
  iv[0] = i0; iv[1] = i1; iv[2] = i2; iv[3] = 0;
  f32x4 wv;
  wv[0] = w0 * inv; wv[1] = w1 * inv; wv[2] = w2 * inv; wv[3] = 0.f;
  *(i32x4*)(idxb + (size_t)p * 4) = iv;
  *(f32x4*)(wb + (size_t)p * 4) = wv;
}

// ---------------- gather+interp -> X0 cols 64..319 (bf16) ----------------
__global__ __launch_bounds__(256) void k_interp(const float* __restrict__ f2t,
                                                const int* __restrict__ idxb,
                                                const float* __restrict__ wb,
                                                unsigned short* __restrict__ X0) {
  const int lane = threadIdx.x & 63, wid = threadIdx.x >> 6;
  const int p = blockIdx.x * 4 + wid;
  const int b = p >> 13;
  i32x4 iv = *(const i32x4*)(idxb + (size_t)p * 4);
  f32x4 wv = *(const f32x4*)(wb + (size_t)p * 4);
  const float* base = f2t + (size_t)b * SS * D2C;
  const int c4 = lane * 4;
  f32x4 a = *(const f32x4*)(base + (size_t)iv[0] * D2C + c4);
  f32x4 c = *(const f32x4*)(base + (size_t)iv[1] * D2C + c4);
  f32x4 e = *(const f32x4*)(base + (size_t)iv[2] * D2C + c4);
  u16x4 o;
#pragma unroll
  for (int j = 0; j < 4; ++j) o[j] = f2b(wv[0] * a[j] + wv[1] * c[j] + wv[2] * e[j]);
  *(u16x4*)(X0 + (size_t)p * C0K + D1C + c4) = o;
}

// ---------------- bf16 MFMA GEMM: C[M][256] = A[M][K] * Bw[256][K]^T + bias ----------------
template <int KDIM, bool TRANSP>
__global__ __launch_bounds__(256) void k_gemm(const unsigned short* __restrict__ A,
                                              const unsigned short* __restrict__ Bw,
                                              const float* __restrict__ bias,
                                              unsigned short* __restrict__ C) {
  __shared__ unsigned short As[128 * 64];
  __shared__ unsigned short Bs[128 * 64];
  const int t = threadIdx.x;
  const int lane = t & 63, wid = t >> 6;
  const int wr = wid >> 1, wc = wid & 1;
  const int m0 = blockIdx.x * 128, n0 = blockIdx.y * 128;
  f32x4 acc[4][4] = {};
  const int lr = lane >> 3;      // 0..7: row within wave's 8-row group
  const int kb = (lane & 7) * 8; // k element offset (8 bf16 = 16B)
  for (int k0 = 0; k0 < KDIM; k0 += 64) {
    __syncthreads();  // previous iteration's LDS reads complete
#pragma unroll
    for (int i = 0; i < 4; ++i) {
      const unsigned short* srcA = A + (size_t)(m0 + i * 32 + wid * 8 + lr) * KDIM + k0 + kb;
      const unsigned short* srcB = Bw + (size_t)(n0 + i * 32 + wid * 8 + lr) * KDIM + k0 + kb;
      __builtin_amdgcn_global_load_lds((const __attribute__((address_space(1))) void*)srcA,
                                       (__attribute__((address_space(3))) void*)&As[(i * 32 + wid * 8) * 64],
                                       16, 0, 0);
      __builtin_amdgcn_global_load_lds((const __attribute__((address_space(1))) void*)srcB,
                                       (__attribute__((address_space(3))) void*)&Bs[(i * 32 + wid * 8) * 64],
                                       16, 0, 0);
    }
    asm volatile("s_waitcnt vmcnt(0)" ::: "memory");
    __syncthreads();
#pragma unroll
    for (int kk = 0; kk < 2; ++kk) {
      const int ko = kk * 32 + (lane >> 4) * 8;
      s16x8 af[4], bf[4];
#pragma unroll
      for (int mi = 0; mi < 4; ++mi)
        af[mi] = *(const s16x8*)&As[(wr * 64 + mi * 16 + (lane & 15)) * 64 + ko];
#pragma unroll
      for (int ni = 0; ni < 4; ++ni)
        bf[ni] = *(const s16x8*)&Bs[(wc * 64 + ni * 16 + (lane & 15)) * 64 + ko];
#pragma unroll
      for (int mi = 0; mi < 4; ++mi)
#pragma unroll
        for (int ni = 0; ni < 4; ++ni)
          acc[mi][ni] =
              __builtin_amdgcn_mfma_f32_16x16x32_bf16(af[mi], bf[ni], acc[mi][ni], 0, 0, 0);
    }
  }
  // epilogue: + bias, store bf16. D frag: col = lane&15 (+16*ni), row = (lane>>4)*4+reg (+16*mi)
  const int cbase = n0 + wc * 64 + (lane & 15);
  float bv[4];
#pragma unroll
  for (int ni = 0; ni < 4; ++ni) bv[ni] = bias[cbase + ni * 16];
  if (!TRANSP) {
#pragma unroll
    for (int mi = 0; mi < 4; ++mi) {
      const size_t rbase = m0 + wr * 64 + mi * 16 + (lane >> 4) * 4;
#pragma unroll
      for (int ni = 0; ni < 4; ++ni) {
        const int cg = cbase + ni * 16;
#pragma unroll
        for (int rj = 0; rj < 4; ++rj)
          C[(rbase + rj) * 256 + cg] = f2b(acc[mi][ni][rj] + bv[ni]);
      }
    }
  } else {
    const size_t bq = m0 >> 13;
    const int nb = (m0 & 8191) + wr * 64 + (lane >> 4) * 4;
#pragma unroll
    for (int mi = 0; mi < 4; ++mi) {
#pragma unroll
      for (int ni = 0; ni < 4; ++ni) {
        const int cg = cbase + ni * 16;
        u16x4 v;
#pragma unroll
        for (int rj = 0; rj < 4; ++rj) v[rj] = f2b(acc[mi][ni][rj] + bv[ni]);
        *(u16x4*)(C + ((bq * 256 + cg) << 13) + nb + mi * 16) = v;
      }
    }
  }
}

// ---------------- BN stats over row-major Y [M][256] bf16 ----------------
__global__ __launch_bounds__(256) void k_stats_rows(const unsigned short* __restrict__ Y,
                                                    float* __restrict__ sums,
                                                    float* __restrict__ ssq) {
  const int c = threadIdx.x;
  const size_t r0 = (size_t)blockIdx.x * 64;
  float s1 = 0.f, s2 = 0.f;
#pragma unroll 8
  for (int j = 0; j < 64; ++j) {
    float v = b2f(Y[(r0 + j) * 256 + c]);
    s1 += v;
    s2 = fmaf(v, v, s2);
  }
  atomicAdd(&sums[c], s1);
  atomicAdd(&ssq[c], s2);
}

// ---------------- BN stats over transposed Yt [B][256][N] bf16 ----------------
__global__ __launch_bounds__(256) void k_stats_t(const unsigned short* __restrict__ Yt,
                                                 float* __restrict__ sums,
                                                 float* __restrict__ ssq) {
  const int t = threadIdx.x;
  const int c = blockIdx.x & 255;
  const size_t base = (size_t)blockIdx.x << 13;
  float s1 = 0.f, s2 = 0.f;
#pragma unroll
  for (int i = 0; i < 8; ++i) {
    u16x4 v4 = *(const u16x4*)(Yt + base + (size_t)(i * 256 + t) * 4);
#pragma unroll
    for (int j = 0; j < 4; ++j) {
      float v = b2f(v4[j]);
      s1 += v;
      s2 = fmaf(v, v, s2);
    }
  }
#pragma unroll
  for (int off = 32; off > 0; off >>= 1) {
    s1 += __shfl_down(s1, off);
    s2 += __shfl_down(s2, off);
  }
  __shared__ float red[8];
  const int lane = t & 63, w = t >> 6;
  if (lane == 0) {
    red[w] = s1;
    red[w + 4] = s2;
  }
  __syncthreads();
  if (t == 0) {
    atomicAdd(&sums[c], red[0] + red[1] + red[2] + red[3]);
    atomicAdd(&ssq[c], red[4] + red[5] + red[6] + red[7]);
  }
}

// ---------------- fold stats + gamma/beta -> per-channel scale/shift ----------------
__global__ void k_params(const float* __restrict__ sums, const float* __restrict__ ssq,
                         const float* __restrict__ gamma, const float* __restrict__ beta,
                         f32x2* __restrict__ P) {
  int c = threadIdx.x;
  float mean = sums[c] * (1.f / 65536.f);
  float var = ssq[c] * (1.f / 65536.f) - mean * mean;
  float sc = gamma[c] * rsqrtf(var + 1e-5f);
  f32x2 pp;
  pp[0] = sc;
  pp[1] = beta[c] - mean * sc;
  P[c] = pp;
}

// ---------------- normalize+relu -> bf16 X1 (row-major) ----------------
__global__ __launch_bounds__(256) void k_norm(const unsigned short* __restrict__ Y,
                                              const f32x2* __restrict__ P,
                                              unsigned short* __restrict__ X) {
  const size_t i4 = ((size_t)blockIdx.x * 256 + threadIdx.x) * 4;
  const int c = (int)(i4 & 255);
  u16x4 y = *(const u16x4*)(Y + i4);
  u16x4 o;
#pragma unroll
  for (int j = 0; j < 4; ++j) {
    f32x2 p = P[c + j];
    o[j] = f2b(fmaxf(fmaf(b2f(y[j]), p[0], p[1]), 0.f));
  }
  *(u16x4*)(X + i4) = o;
}

// ---------------- normalize+relu -> fp32 out (already [B][256][N]) ----------------
__global__ __launch_bounds__(256) void k_final(const unsigned short* __restrict__ Yt,
                                               const f32x2* __restrict__ P,
                                               float* __restrict__ out) {
  const size_t i4 = ((size_t)blockIdx.x * 256 + threadIdx.x) * 4;
  const int c = (int)((i4 >> 13) & 255);
  const f32x2 p = P[c];
  u16x4 y = *(const u16x4*)(Yt + i4);
  f32x4 o;
#pragma unroll
  for (int j = 0; j < 4; ++j) o[j] = fmaxf(fmaf(b2f(y[j]), p[0], p[1]), 0.f);
  *(f32x4*)(out + i4) = o;
}

extern "C" void kernel_launch(void* const* d_in, const int* in_sizes, int n_in,
                              void* d_out, int out_size, void* d_ws, size_t ws_size,
                              hipStream_t stream) {
  const float* xyz1 = (const float*)d_in[0];
  const float* xyz2 = (const float*)d_in[1];
  const float* pts1 = (const float*)d_in[2];
  const float* pts2 = (const float*)d_in[3];
  const float* W0 = (const float*)d_in[4];
  const float* b0 = (const float*)d_in[5];
  const float* g0 = (const float*)d_in[6];
  const float* be0 = (const float*)d_in[7];
  const float* W1 = (const float*)d_in[8];
  const float* b1 = (const float*)d_in[9];
  const float* g1 = (const float*)d_in[10];
  const float* be1 = (const float*)d_in[11];
  float* out = (float*)d_out;
  char* ws = (char*)d_ws;

  // workspace layout (aliased; peak ~90.3 MB):
  float* f2t = (float*)(ws + 0);                          // 16 MB, live tr_f2t..interp
  int* idxb = (int*)(ws + 16777216);                      // 1 MB,  live merge..interp
  float* wb = (float*)(ws + 17825792);                    // 1 MB,  live merge..interp
  unsigned short* X0 = (unsigned short*)(ws + 18874368);  // 40 MB, live tr_x0..gemm0
  unsigned short* Y0 = (unsigned short*)(ws + 60817408);  // 32 MB, live gemm0..norm
  unsigned short* X1 = (unsigned short*)(ws + 0);         // 32 MB, live norm..gemm1
  unsigned short* Yt = (unsigned short*)(ws + 60817408);  // 32 MB, live gemm1..final
  f32x4* pd = (f32x4*)(ws + 60817408);                    // 8 MB,  live dist..merge (aliases Y0)
  i32x4* pi = (i32x4*)(ws + 69206016);                    // 8 MB,  live dist..merge
  unsigned short* W0b = (unsigned short*)(ws + 94371840);
  unsigned short* W1b = (unsigned short*)(ws + 94535680);
  float* sums0 = (float*)(ws + 94666752);
  float* ssq0 = sums0 + 256;
  float* sums1 = sums0 + 512;
  float* ssq1 = sums0 + 768;
  f32x2* P0 = (f32x2*)(ws + 94670848);
  f32x2* P1 = (f32x2*)(ws + 94672896);

  hipMemsetAsync(sums0, 0, 4096, stream);
  k_castw<<<80, 256, 0, stream>>>(W0, W0b, 81920);
  k_castw<<<64, 256, 0, stream>>>(W1, W1b, 65536);
  k_tr_f2t<<<dim3(32, 4, BB), 256, 0, stream>>>(pts2, f2t);
  k_dist<<<dim3(8, SCHUNKS, BB), 256, 0, stream>>>(xyz1, xyz2, pd, pi);
  k_merge<<<256, 256, 0, stream>>>(pd, pi, idxb, wb);
  k_tr_x0<<<dim3(128, BB), 256, 0, stream>>>(pts1, X0);
  k_interp<<<16384, 256, 0, stream>>>(f2t, idxb, wb, X0);
  k_gemm<320, false><<<dim3(512, 2), 256, 0, stream>>>(X0, W0b, b0, Y0);
  k_stats_rows<<<1024, 256, 0, stream>>>(Y0, sums0, ssq0);
  k_params<<<1, 256, 0, stream>>>(sums0, ssq0, g0, be0, P0);
  k_norm<<<16384, 256, 0, stream>>>(Y0, P0, X1);
  k_gemm<256, true><<<dim3(512, 2), 256, 0, stream>>>(X1, W1b, b1, Yt);
  k_stats_t<<<2048, 256, 0, stream>>>(Yt, sums1, ssq1);
  k_params<<<1, 256, 0, stream>>>(sums1, ssq1, g1, be1, P1);
  k_final<<<16384, 256, 0, stream>>>(Yt, P1, out);
}

// Round 4
// 237.253 us; speedup vs baseline: 1.0783x; 1.0783x over previous
//
#include <hip/hip_runtime.h>

using f32x4 = __attribute__((ext_vector_type(4))) float;
using f32x2 = __attribute__((ext_vector_type(2))) float;
using s16x8 = __attribute__((ext_vector_type(8))) short;
using u16x4 = __attribute__((ext_vector_type(4))) unsigned short;
using i32x4 = __attribute__((ext_vector_type(4))) int;

#define BB 8
#define NPTS 8192
#define SS 2048
#define D1C 64
#define D2C 256
#define C0K 320
#define MM 65536
#define SCHUNKS 16
#define SCH (SS / SCHUNKS)  // 128

__device__ __forceinline__ float b2f(unsigned short h) {
  unsigned int u = ((unsigned int)h) << 16;
  return __builtin_bit_cast(float, u);
}
__device__ __forceinline__ unsigned short f2b(float f) {
  unsigned int u = __builtin_bit_cast(unsigned int, f);
  u += 0x7fffu + ((u >> 16) & 1u);
  return (unsigned short)(u >> 16);
}

// top-3 insert: distances via med3/min (3 VALU), indices via cmp+cndmask (strict < => stable)
__device__ __forceinline__ void ins3(float& dd0, float& dd1, float& dd2, int& ii0, int& ii1,
                                     int& ii2, float d, int s) {
  bool c0 = d < dd0, c1 = d < dd1, c2 = d < dd2;
  ii2 = c1 ? ii1 : (c2 ? s : ii2);
  ii1 = c0 ? ii0 : (c1 ? s : ii1);
  ii0 = c0 ? s : ii0;
  dd2 = __builtin_amdgcn_fmed3f(dd1, dd2, d);
  dd1 = __builtin_amdgcn_fmed3f(dd0, dd1, d);
  dd0 = fminf(dd0, d);
}

// ---------------- cast fp32 weights -> bf16 ----------------
__global__ __launch_bounds__(256) void k_castw(const float* __restrict__ src,
                                               unsigned short* __restrict__ dst, int n) {
  int i4 = (blockIdx.x * 256 + threadIdx.x) * 4;
  if (i4 >= n) return;
  f32x4 v = *(const f32x4*)(src + i4);
  u16x4 o;
#pragma unroll
  for (int j = 0; j < 4; ++j) o[j] = f2b(v[j]);
  *(u16x4*)(dst + i4) = o;
}

// ---------------- transpose points2 [B][256][S] -> f2t [B][S][256] ----------------
__global__ __launch_bounds__(256) void k_tr_f2t(const float* __restrict__ pts2,
                                                float* __restrict__ f2t) {
  __shared__ float tile[64 * 65];
  const int t = threadIdx.x;
  const int s0 = blockIdx.x * 64, c0 = blockIdx.y * 64, b = blockIdx.z;
#pragma unroll
  for (int i = 0; i < 4; ++i) {
    const int cl = i * 16 + (t >> 4);
    const int s4 = (t & 15) * 4;
    f32x4 v = *(const f32x4*)(pts2 + ((size_t)(b * D2C + c0 + cl)) * SS + s0 + s4);
#pragma unroll
    for (int j = 0; j < 4; ++j) tile[cl * 65 + s4 + j] = v[j];
  }
  __syncthreads();
#pragma unroll
  for (int i = 0; i < 4; ++i) {
    const int sl = i * 16 + (t >> 4);
    const int c4 = (t & 15) * 4;
    f32x4 o;
#pragma unroll
    for (int j = 0; j < 4; ++j) o[j] = tile[(c4 + j) * 65 + sl];
    *(f32x4*)(f2t + ((size_t)(b * SS + s0 + sl)) * D2C + c0 + c4) = o;
  }
}

// ---------------- transpose points1 [B][64][N] -> X0 cols 0..63 (bf16) ----------------
__global__ __launch_bounds__(256) void k_tr_x0(const float* __restrict__ pts1,
                                               unsigned short* __restrict__ X0) {
  __shared__ float tile[64 * 65];
  const int t = threadIdx.x;
  const int n0 = blockIdx.x * 64, b = blockIdx.y;
#pragma unroll
  for (int i = 0; i < 4; ++i) {
    const int cl = i * 16 + (t >> 4);
    const int n4 = (t & 15) * 4;
    f32x4 v = *(const f32x4*)(pts1 + ((size_t)(b * D1C + cl)) * NPTS + n0 + n4);
#pragma unroll
    for (int j = 0; j < 4; ++j) tile[cl * 65 + n4 + j] = v[j];
  }
  __syncthreads();
#pragma unroll
  for (int i = 0; i < 4; ++i) {
    const int nl = i * 16 + (t >> 4);
    const int c4 = (t & 15) * 4;
    u16x4 o;
#pragma unroll
    for (int j = 0; j < 4; ++j) o[j] = f2b(tile[(c4 + j) * 65 + nl]);
    *(u16x4*)(X0 + ((size_t)(b * NPTS + n0 + nl)) * C0K + c4) = o;
  }
}

// ---------------- 3-NN partial: per S-chunk top-3, 4 query pts/thread ----------------
// comparison key d' = |p2|^2 - 2<p1,p2>  (drop |p1|^2: constant per query, monotone)
__global__ __launch_bounds__(256) void k_dist(const float* __restrict__ xyz1,
                                              const float* __restrict__ xyz2,
                                              f32x4* __restrict__ pd,
                                              i32x4* __restrict__ pi) {
  __shared__ f32x4 p2[SCH];
  const int t = threadIdx.x;
  const int b = blockIdx.z, cy = blockIdx.y, ss0 = cy * SCH;
  const float* xz2 = xyz2 + (size_t)b * 3 * SS;
  if (t < SCH) {
    const int s = t;
    float x = xz2[ss0 + s], y = xz2[SS + ss0 + s], z = xz2[2 * SS + ss0 + s];
    f32x4 q;
    q[0] = x; q[1] = y; q[2] = z; q[3] = x * x + y * y + z * z;
    p2[s] = q;
  }
  __syncthreads();
  const float* xz1 = xyz1 + (size_t)b * 3 * NPTS;
  const int nb = blockIdx.x * 1024 + t;
  float tx[4], ty[4], tz[4], d0[4], d1[4], d2[4];
  int i0[4], i1[4], i2[4];
#pragma unroll
  for (int j = 0; j < 4; ++j) {
    const int n = nb + j * 256;
    tx[j] = -2.f * xz1[n];
    ty[j] = -2.f * xz1[NPTS + n];
    tz[j] = -2.f * xz1[2 * NPTS + n];
    d0[j] = d1[j] = d2[j] = 1e30f;
    i0[j] = i1[j] = i2[j] = 0;
  }
#pragma unroll 4
  for (int s = 0; s < SCH; ++s) {
    const f32x4 q = p2[s];
    const int sg = ss0 + s;
#pragma unroll
    for (int j = 0; j < 4; ++j) {
      float d = fmaf(tx[j], q[0], fmaf(ty[j], q[1], fmaf(tz[j], q[2], q[3])));
      ins3(d0[j], d1[j], d2[j], i0[j], i1[j], i2[j], d, sg);
    }
  }
#pragma unroll
  for (int j = 0; j < 4; ++j) {
    const int n = nb + j * 256;
    const float r1 = 0.25f * (tx[j] * tx[j] + ty[j] * ty[j] + tz[j] * tz[j]);
    const size_t p = ((size_t)(b * SCHUNKS + cy)) * NPTS + n;
    f32x4 dv;
    dv[0] = d0[j]; dv[1] = d1[j]; dv[2] = d2[j]; dv[3] = r1;
    i32x4 iv;
    iv[0] = i0[j]; iv[1] = i1[j]; iv[2] = i2[j]; iv[3] = 0;
    pd[p] = dv;
    pi[p] = iv;
  }
}

// ---------------- merge partial top-3 -> final idx + weights ----------------
__global__ __launch_bounds__(256) void k_merge(const f32x4* __restrict__ pd,
                                               const i32x4* __restrict__ pi,
                                               int* __restrict__ idxb,
                                               float* __restrict__ wb) {
  const int p = blockIdx.x * 256 + threadIdx.x;
  const int b = p >> 13, n = p & 8191;
  const size_t base = ((size_t)(b * SCHUNKS)) * NPTS + n;
  f32x4 dv = pd[base];
  i32x4 ivv = pi[base];
  const float r1 = dv[3];
  float d0 = dv[0], d1 = dv[1], d2 = dv[2];
  int i0 = ivv[0], i1 = ivv[1], i2 = ivv[2];
#pragma unroll
  for (int c = 1; c < SCHUNKS; ++c) {
    f32x4 dc = pd[base + (size_t)c * NPTS];
    i32x4 ic = pi[base + (size_t)c * NPTS];
    ins3(d0, d1, d2, i0, i1, i2, dc[0], ic[0]);
    ins3(d0, d1, d2, i0, i1, i2, dc[1], ic[1]);
    ins3(d0, d1, d2, i0, i1, i2, dc[2], ic[2]);
  }
  float w0 = 1.f / (d0 + r1 + 1e-8f), w1 = 1.f / (d1 + r1 + 1e-8f), w2 = 1.f / (d2 + r1 + 1e-8f);
  float inv = 1.f / (w0 + w1 + w2);
  i32x4 iv;
  iv[0] = i0; iv[1] = i1; iv[2] = i2; iv[3] = 0;
  f32x4 wv;
  wv[0] = w0 * inv; wv[1] = w1 * inv; wv[2] = w2 * inv; wv[3] = 0.f;
  *(i32x4*)(idxb + (size_t)p * 4) = iv;
  *(f32x4*)(wb + (size_t)p * 4) = wv;
}

// ---------------- gather+interp -> X0 cols 64..319 (bf16) ----------------
__global__ __launch_bounds__(256) void k_interp(const float* __restrict__ f2t,
                                                const int* __restrict__ idxb,
                                                const float* __restrict__ wb,
                                                unsigned short* __restrict__ X0) {
  const int lane = threadIdx.x & 63, wid = threadIdx.x >> 6;
  const int p = blockIdx.x * 4 + wid;
  const int b = p >> 13;
  i32x4 iv = *(const i32x4*)(idxb + (size_t)p * 4);
  f32x4 wv = *(const f32x4*)(wb + (size_t)p * 4);
  const float* base = f2t + (size_t)b * SS * D2C;
  const int c4 = lane * 4;
  f32x4 a = *(const f32x4*)(base + (size_t)iv[0] * D2C + c4);
  f32x4 c = *(const f32x4*)(base + (size_t)iv[1] * D2C + c4);
  f32x4 e = *(const f32x4*)(base + (size_t)iv[2] * D2C + c4);
  u16x4 o;
#pragma unroll
  for (int j = 0; j < 4; ++j) o[j] = f2b(wv[0] * a[j] + wv[1] * c[j] + wv[2] * e[j]);
  *(u16x4*)(X0 + (size_t)p * C0K + D1C + c4) = o;
}

// ---------------- bf16 MFMA GEMM: C[M][256] = A[M][K] * Bw[256][K]^T + bias ----------------
template <int KDIM, bool TRANSP>
__global__ __launch_bounds__(256) void k_gemm(const unsigned short* __restrict__ A,
                                              const unsigned short* __restrict__ Bw,
                                              const float* __restrict__ bias,
                                              unsigned short* __restrict__ C) {
  __shared__ unsigned short As[128 * 64];
  __shared__ unsigned short Bs[128 * 64];
  const int t = threadIdx.x;
  const int lane = t & 63, wid = t >> 6;
  const int wr = wid >> 1, wc = wid & 1;
  const int m0 = blockIdx.x * 128, n0 = blockIdx.y * 128;
  f32x4 acc[4][4] = {};
  const int lr = lane >> 3;      // 0..7: row within wave's 8-row group
  const int kb = (lane & 7) * 8; // k element offset (8 bf16 = 16B)
  for (int k0 = 0; k0 < KDIM; k0 += 64) {
    __syncthreads();  // previous iteration's LDS reads complete
#pragma unroll
    for (int i = 0; i < 4; ++i) {
      const unsigned short* srcA = A + (size_t)(m0 + i * 32 + wid * 8 + lr) * KDIM + k0 + kb;
      const unsigned short* srcB = Bw + (size_t)(n0 + i * 32 + wid * 8 + lr) * KDIM + k0 + kb;
      __builtin_amdgcn_global_load_lds((const __attribute__((address_space(1))) void*)srcA,
                                       (__attribute__((address_space(3))) void*)&As[(i * 32 + wid * 8) * 64],
                                       16, 0, 0);
      __builtin_amdgcn_global_load_lds((const __attribute__((address_space(1))) void*)srcB,
                                       (__attribute__((address_space(3))) void*)&Bs[(i * 32 + wid * 8) * 64],
                                       16, 0, 0);
    }
    asm volatile("s_waitcnt vmcnt(0)" ::: "memory");
    __syncthreads();
#pragma unroll
    for (int kk = 0; kk < 2; ++kk) {
      const int ko = kk * 32 + (lane >> 4) * 8;
      s16x8 af[4], bf[4];
#pragma unroll
      for (int mi = 0; mi < 4; ++mi)
        af[mi] = *(const s16x8*)&As[(wr * 64 + mi * 16 + (lane & 15)) * 64 + ko];
#pragma unroll
      for (int ni = 0; ni < 4; ++ni)
        bf[ni] = *(const s16x8*)&Bs[(wc * 64 + ni * 16 + (lane & 15)) * 64 + ko];
#pragma unroll
      for (int mi = 0; mi < 4; ++mi)
#pragma unroll
        for (int ni = 0; ni < 4; ++ni)
          acc[mi][ni] =
              __builtin_amdgcn_mfma_f32_16x16x32_bf16(af[mi], bf[ni], acc[mi][ni], 0, 0, 0);
    }
  }
  // epilogue: + bias, store bf16. D frag: col = lane&15 (+16*ni), row = (lane>>4)*4+reg (+16*mi)
  const int cbase = n0 + wc * 64 + (lane & 15);
  float bv[4];
#pragma unroll
  for (int ni = 0; ni < 4; ++ni) bv[ni] = bias[cbase + ni * 16];
  if (!TRANSP) {
#pragma unroll
    for (int mi = 0; mi < 4; ++mi) {
      const size_t rbase = m0 + wr * 64 + mi * 16 + (lane >> 4) * 4;
#pragma unroll
      for (int ni = 0; ni < 4; ++ni) {
        const int cg = cbase + ni * 16;
#pragma unroll
        for (int rj = 0; rj < 4; ++rj)
          C[(rbase + rj) * 256 + cg] = f2b(acc[mi][ni][rj] + bv[ni]);
      }
    }
  } else {
    const size_t bq = m0 >> 13;
    const int nb = (m0 & 8191) + wr * 64 + (lane >> 4) * 4;
#pragma unroll
    for (int mi = 0; mi < 4; ++mi) {
#pragma unroll
      for (int ni = 0; ni < 4; ++ni) {
        const int cg = cbase + ni * 16;
        u16x4 v;
#pragma unroll
        for (int rj = 0; rj < 4; ++rj) v[rj] = f2b(acc[mi][ni][rj] + bv[ni]);
        *(u16x4*)(C + ((bq * 256 + cg) << 13) + nb + mi * 16) = v;
      }
    }
  }
}

// ---------------- BN stats over row-major Y [M][256] bf16 ----------------
__global__ __launch_bounds__(256) void k_stats_rows(const unsigned short* __restrict__ Y,
                                                    float* __restrict__ sums,
                                                    float* __restrict__ ssq) {
  const int c = threadIdx.x;
  const size_t r0 = (size_t)blockIdx.x * 64;
  float s1 = 0.f, s2 = 0.f;
#pragma unroll 8
  for (int j = 0; j < 64; ++j) {
    float v = b2f(Y[(r0 + j) * 256 + c]);
    s1 += v;
    s2 = fmaf(v, v, s2);
  }
  atomicAdd(&sums[c], s1);
  atomicAdd(&ssq[c], s2);
}

// ---------------- BN stats over transposed Yt [B][256][N] bf16 ----------------
__global__ __launch_bounds__(256) void k_stats_t(const unsigned short* __restrict__ Yt,
                                                 float* __restrict__ sums,
                                                 float* __restrict__ ssq) {
  const int t = threadIdx.x;
  const int c = blockIdx.x & 255;
  const size_t base = (size_t)blockIdx.x << 13;
  float s1 = 0.f, s2 = 0.f;
#pragma unroll
  for (int i = 0; i < 8; ++i) {
    u16x4 v4 = *(const u16x4*)(Yt + base + (size_t)(i * 256 + t) * 4);
#pragma unroll
    for (int j = 0; j < 4; ++j) {
      float v = b2f(v4[j]);
      s1 += v;
      s2 = fmaf(v, v, s2);
    }
  }
#pragma unroll
  for (int off = 32; off > 0; off >>= 1) {
    s1 += __shfl_down(s1, off);
    s2 += __shfl_down(s2, off);
  }
  __shared__ float red[8];
  const int lane = t & 63, w = t >> 6;
  if (lane == 0) {
    red[w] = s1;
    red[w + 4] = s2;
  }
  __syncthreads();
  if (t == 0) {
    atomicAdd(&sums[c], red[0] + red[1] + red[2] + red[3]);
    atomicAdd(&ssq[c], red[4] + red[5] + red[6] + red[7]);
  }
}

// ---------------- fold stats + gamma/beta -> per-channel scale/shift ----------------
__global__ void k_params(const float* __restrict__ sums, const float* __restrict__ ssq,
                         const float* __restrict__ gamma, const float* __restrict__ beta,
                         f32x2* __restrict__ P) {
  int c = threadIdx.x;
  float mean = sums[c] * (1.f / 65536.f);
  float var = ssq[c] * (1.f / 65536.f) - mean * mean;
  float sc = gamma[c] * rsqrtf(var + 1e-5f);
  f32x2 pp;
  pp[0] = sc;
  pp[1] = beta[c] - mean * sc;
  P[c] = pp;
}

// ---------------- normalize+relu -> bf16 X1 (row-major) ----------------
__global__ __launch_bounds__(256) void k_norm(const unsigned short* __restrict__ Y,
                                              const f32x2* __restrict__ P,
                                              unsigned short* __restrict__ X) {
  const size_t i4 = ((size_t)blockIdx.x * 256 + threadIdx.x) * 4;
  const int c = (int)(i4 & 255);
  u16x4 y = *(const u16x4*)(Y + i4);
  u16x4 o;
#pragma unroll
  for (int j = 0; j < 4; ++j) {
    f32x2 p = P[c + j];
    o[j] = f2b(fmaxf(fmaf(b2f(y[j]), p[0], p[1]), 0.f));
  }
  *(u16x4*)(X + i4) = o;
}

// ---------------- normalize+relu -> fp32 out (already [B][256][N]) ----------------
__global__ __launch_bounds__(256) void k_final(const unsigned short* __restrict__ Yt,
                                               const f32x2* __restrict__ P,
                                               float* __restrict__ out) {
  const size_t i4 = ((size_t)blockIdx.x * 256 + threadIdx.x) * 4;
  const int c = (int)((i4 >> 13) & 255);
  const f32x2 p = P[c];
  u16x4 y = *(const u16x4*)(Yt + i4);
  f32x4 o;
#pragma unroll
  for (int j = 0; j < 4; ++j) o[j] = fmaxf(fmaf(b2f(y[j]), p[0], p[1]), 0.f);
  *(f32x4*)(out + i4) = o;
}

extern "C" void kernel_launch(void* const* d_in, const int* in_sizes, int n_in,
                              void* d_out, int out_size, void* d_ws, size_t ws_size,
                              hipStream_t stream) {
  const float* xyz1 = (const float*)d_in[0];
  const float* xyz2 = (const float*)d_in[1];
  const float* pts1 = (const float*)d_in[2];
  const float* pts2 = (const float*)d_in[3];
  const float* W0 = (const float*)d_in[4];
  const float* b0 = (const float*)d_in[5];
  const float* g0 = (const float*)d_in[6];
  const float* be0 = (const float*)d_in[7];
  const float* W1 = (const float*)d_in[8];
  const float* b1 = (const float*)d_in[9];
  const float* g1 = (const float*)d_in[10];
  const float* be1 = (const float*)d_in[11];
  float* out = (float*)d_out;
  char* ws = (char*)d_ws;

  // workspace layout (aliased; peak ~94.7 MB):
  float* f2t = (float*)(ws + 0);                          // 16 MB, live tr_f2t..interp
  int* idxb = (int*)(ws + 16777216);                      // 1 MB,  live merge..interp
  float* wb = (float*)(ws + 17825792);                    // 1 MB,  live merge..interp
  unsigned short* X0 = (unsigned short*)(ws + 18874368);  // 40 MB, live tr_x0..gemm0
  unsigned short* Y0 = (unsigned short*)(ws + 60817408);  // 32 MB, live gemm0..norm
  unsigned short* X1 = (unsigned short*)(ws + 0);         // 32 MB, live norm..gemm1
  unsigned short* Yt = (unsigned short*)(ws + 60817408);  // 32 MB, live gemm1..final
  f32x4* pd = (f32x4*)(ws + 60817408);                    // 16 MB, live dist..merge (aliases Y0)
  i32x4* pi = (i32x4*)(ws + 77594624);                    // 16 MB, live dist..merge
  unsigned short* W0b = (unsigned short*)(ws + 94371840);
  unsigned short* W1b = (unsigned short*)(ws + 94535680);
  float* sums0 = (float*)(ws + 94666752);
  float* ssq0 = sums0 + 256;
  float* sums1 = sums0 + 512;
  float* ssq1 = sums0 + 768;
  f32x2* P0 = (f32x2*)(ws + 94670848);
  f32x2* P1 = (f32x2*)(ws + 94672896);

  hipMemsetAsync(sums0, 0, 4096, stream);
  k_castw<<<80, 256, 0, stream>>>(W0, W0b, 81920);
  k_castw<<<64, 256, 0, stream>>>(W1, W1b, 65536);
  k_tr_f2t<<<dim3(32, 4, BB), 256, 0, stream>>>(pts2, f2t);
  k_dist<<<dim3(8, SCHUNKS, BB), 256, 0, stream>>>(xyz1, xyz2, pd, pi);
  k_merge<<<256, 256, 0, stream>>>(pd, pi, idxb, wb);
  k_tr_x0<<<dim3(128, BB), 256, 0, stream>>>(pts1, X0);
  k_interp<<<16384, 256, 0, stream>>>(f2t, idxb, wb, X0);
  k_gemm<320, false><<<dim3(512, 2), 256, 0, stream>>>(X0, W0b, b0, Y0);
  k_stats_rows<<<1024, 256, 0, stream>>>(Y0, sums0, ssq0);
  k_params<<<1, 256, 0, stream>>>(sums0, ssq0, g0, be0, P0);
  k_norm<<<16384, 256, 0, stream>>>(Y0, P0, X1);
  k_gemm<256, true><<<dim3(512, 2), 256, 0, stream>>>(X1, W1b, b1, Yt);
  k_stats_t<<<2048, 256, 0, stream>>>(Yt, sums1, ssq1);
  k_params<<<1, 256, 0, stream>>>(sums1, ssq1, g1, be1, P1);
  k_final<<<16384, 256, 0, stream>>>(Yt, P1, out);
}

// Round 5
// 225.118 us; speedup vs baseline: 1.1365x; 1.0539x over previous
//
#include <hip/hip_runtime.h>

using f32x4 = __attribute__((ext_vector_type(4))) float;
using f32x2 = __attribute__((ext_vector_type(2))) float;
using s16x8 = __attribute__((ext_vector_type(8))) short;
using u16x4 = __attribute__((ext_vector_type(4))) unsigned short;
using i32x4 = __attribute__((ext_vector_type(4))) int;

#define BB 8
#define NPTS 8192
#define SS 2048
#define D1C 64
#define D2C 256
#define C0K 320
#define MM 65536
#define SCHUNKS 16
#define SCH (SS / SCHUNKS)  // 128

__device__ __forceinline__ float b2f(unsigned short h) {
  unsigned int u = ((unsigned int)h) << 16;
  return __builtin_bit_cast(float, u);
}
__device__ __forceinline__ unsigned short f2b(float f) {
  unsigned int u = __builtin_bit_cast(unsigned int, f);
  u += 0x7fffu + ((u >> 16) & 1u);
  return (unsigned short)(u >> 16);
}

// top-3 insert: distances via med3/min (3 VALU), indices via cmp+cndmask (strict < => stable)
__device__ __forceinline__ void ins3(float& dd0, float& dd1, float& dd2, int& ii0, int& ii1,
                                     int& ii2, float d, int s) {
  bool c0 = d < dd0, c1 = d < dd1, c2 = d < dd2;
  ii2 = c1 ? ii1 : (c2 ? s : ii2);
  ii1 = c0 ? ii0 : (c1 ? s : ii1);
  ii0 = c0 ? s : ii0;
  dd2 = __builtin_amdgcn_fmed3f(dd1, dd2, d);
  dd1 = __builtin_amdgcn_fmed3f(dd0, dd1, d);
  dd0 = fminf(dd0, d);
}

// ---------------- cast fp32 weights -> bf16 ----------------
__global__ __launch_bounds__(256) void k_castw(const float* __restrict__ src,
                                               unsigned short* __restrict__ dst, int n) {
  int i4 = (blockIdx.x * 256 + threadIdx.x) * 4;
  if (i4 >= n) return;
  f32x4 v = *(const f32x4*)(src + i4);
  u16x4 o;
#pragma unroll
  for (int j = 0; j < 4; ++j) o[j] = f2b(v[j]);
  *(u16x4*)(dst + i4) = o;
}

// ---------------- transpose points2 [B][256][S] -> f2t [B][S][256] ----------------
__global__ __launch_bounds__(256) void k_tr_f2t(const float* __restrict__ pts2,
                                                float* __restrict__ f2t) {
  __shared__ float tile[64 * 65];
  const int t = threadIdx.x;
  const int s0 = blockIdx.x * 64, c0 = blockIdx.y * 64, b = blockIdx.z;
#pragma unroll
  for (int i = 0; i < 4; ++i) {
    const int cl = i * 16 + (t >> 4);
    const int s4 = (t & 15) * 4;
    f32x4 v = *(const f32x4*)(pts2 + ((size_t)(b * D2C + c0 + cl)) * SS + s0 + s4);
#pragma unroll
    for (int j = 0; j < 4; ++j) tile[cl * 65 + s4 + j] = v[j];
  }
  __syncthreads();
#pragma unroll
  for (int i = 0; i < 4; ++i) {
    const int sl = i * 16 + (t >> 4);
    const int c4 = (t & 15) * 4;
    f32x4 o;
#pragma unroll
    for (int j = 0; j < 4; ++j) o[j] = tile[(c4 + j) * 65 + sl];
    *(f32x4*)(f2t + ((size_t)(b * SS + s0 + sl)) * D2C + c0 + c4) = o;
  }
}

// ---------------- transpose points1 [B][64][N] -> X0 cols 0..63 (bf16) ----------------
__global__ __launch_bounds__(256) void k_tr_x0(const float* __restrict__ pts1,
                                               unsigned short* __restrict__ X0) {
  __shared__ float tile[64 * 65];
  const int t = threadIdx.x;
  const int n0 = blockIdx.x * 64, b = blockIdx.y;
#pragma unroll
  for (int i = 0; i < 4; ++i) {
    const int cl = i * 16 + (t >> 4);
    const int n4 = (t & 15) * 4;
    f32x4 v = *(const f32x4*)(pts1 + ((size_t)(b * D1C + cl)) * NPTS + n0 + n4);
#pragma unroll
    for (int j = 0; j < 4; ++j) tile[cl * 65 + n4 + j] = v[j];
  }
  __syncthreads();
#pragma unroll
  for (int i = 0; i < 4; ++i) {
    const int nl = i * 16 + (t >> 4);
    const int c4 = (t & 15) * 4;
    u16x4 o;
#pragma unroll
    for (int j = 0; j < 4; ++j) o[j] = f2b(tile[(c4 + j) * 65 + nl]);
    *(u16x4*)(X0 + ((size_t)(b * NPTS + n0 + nl)) * C0K + c4) = o;
  }
}

// ---------------- 3-NN partial: per S-chunk top-3, 4 query pts/thread ----------------
__global__ __launch_bounds__(256) void k_dist(const float* __restrict__ xyz1,
                                              const float* __restrict__ xyz2,
                                              f32x4* __restrict__ pd,
                                              i32x4* __restrict__ pi) {
  __shared__ f32x4 p2[SCH];
  const int t = threadIdx.x;
  const int b = blockIdx.z, cy = blockIdx.y, ss0 = cy * SCH;
  const float* xz2 = xyz2 + (size_t)b * 3 * SS;
  if (t < SCH) {
    const int s = t;
    float x = xz2[ss0 + s], y = xz2[SS + ss0 + s], z = xz2[2 * SS + ss0 + s];
    f32x4 q;
    q[0] = x; q[1] = y; q[2] = z; q[3] = x * x + y * y + z * z;
    p2[s] = q;
  }
  __syncthreads();
  const float* xz1 = xyz1 + (size_t)b * 3 * NPTS;
  const int nb = blockIdx.x * 1024 + t;
  float tx[4], ty[4], tz[4], d0[4], d1[4], d2[4];
  int i0[4], i1[4], i2[4];
#pragma unroll
  for (int j = 0; j < 4; ++j) {
    const int n = nb + j * 256;
    tx[j] = -2.f * xz1[n];
    ty[j] = -2.f * xz1[NPTS + n];
    tz[j] = -2.f * xz1[2 * NPTS + n];
    d0[j] = d1[j] = d2[j] = 1e30f;
    i0[j] = i1[j] = i2[j] = 0;
  }
#pragma unroll 4
  for (int s = 0; s < SCH; ++s) {
    const f32x4 q = p2[s];
    const int sg = ss0 + s;
#pragma unroll
    for (int j = 0; j < 4; ++j) {
      float d = fmaf(tx[j], q[0], fmaf(ty[j], q[1], fmaf(tz[j], q[2], q[3])));
      ins3(d0[j], d1[j], d2[j], i0[j], i1[j], i2[j], d, sg);
    }
  }
#pragma unroll
  for (int j = 0; j < 4; ++j) {
    const int n = nb + j * 256;
    const float r1 = 0.25f * (tx[j] * tx[j] + ty[j] * ty[j] + tz[j] * tz[j]);
    const size_t p = ((size_t)(b * SCHUNKS + cy)) * NPTS + n;
    f32x4 dv;
    dv[0] = d0[j]; dv[1] = d1[j]; dv[2] = d2[j]; dv[3] = r1;
    i32x4 iv;
    iv[0] = i0[j]; iv[1] = i1[j]; iv[2] = i2[j]; iv[3] = 0;
    pd[p] = dv;
    pi[p] = iv;
  }
}

// ---------------- merge partial top-3 -> final idx + weights ----------------
__global__ __launch_bounds__(256) void k_merge(const f32x4* __restrict__ pd,
                                               const i32x4* __restrict__ pi,
                                               int* __restrict__ idxb,
                                               float* __restrict__ wb) {
  const int p = blockIdx.x * 256 + threadIdx.x;
  const int b = p >> 13, n = p & 8191;
  const size_t base = ((size_t)(b * SCHUNKS)) * NPTS + n;
  f32x4 dv = pd[base];
  i32x4 ivv = pi[base];
  const float r1 = dv[3];
  float d0 = dv[0], d1 = dv[1], d2 = dv[2];
  int i0 = ivv[0], i1 = ivv[1], i2 = ivv[2];
#pragma unroll
  for (int c = 1; c < SCHUNKS; ++c) {
    f32x4 dc = pd[base + (size_t)c * NPTS];
    i32x4 ic = pi[base + (size_t)c * NPTS];
    ins3(d0, d1, d2, i0, i1, i2, dc[0], ic[0]);
    ins3(d0, d1, d2, i0, i1, i2, dc[1], ic[1]);
    ins3(d0, d1, d2, i0, i1, i2, dc[2], ic[2]);
  }
  float w0 = 1.f / (d0 + r1 + 1e-8f), w1 = 1.f / (d1 + r1 + 1e-8f), w2 = 1.f / (d2 + r1 + 1e-8f);
  float inv = 1.f / (w0 + w1 + w2);
  i32x4 iv;
  iv[0] = i0; iv[1] = i1; iv[2] = i2; iv[3] = 0;
  f32x4 wv;
  wv[0] = w0 * inv; wv[1] = w1 * inv; wv[2] = w2 * inv; wv[3] = 0.f;
  *(i32x4*)(idxb + (size_t)p * 4) = iv;
  *(f32x4*)(wb + (size_t)p * 4) = wv;
}

// ---------------- gather+interp -> X0 cols 64..319 (bf16) ----------------
__global__ __launch_bounds__(256) void k_interp(const float* __restrict__ f2t,
                                                const int* __restrict__ idxb,
                                                const float* __restrict__ wb,
                                                unsigned short* __restrict__ X0) {
  const int lane = threadIdx.x & 63, wid = threadIdx.x >> 6;
  const int p = blockIdx.x * 4 + wid;
  const int b = p >> 13;
  i32x4 iv = *(const i32x4*)(idxb + (size_t)p * 4);
  f32x4 wv = *(const f32x4*)(wb + (size_t)p * 4);
  const float* base = f2t + (size_t)b * SS * D2C;
  const int c4 = lane * 4;
  f32x4 a = *(const f32x4*)(base + (size_t)iv[0] * D2C + c4);
  f32x4 c = *(const f32x4*)(base + (size_t)iv[1] * D2C + c4);
  f32x4 e = *(const f32x4*)(base + (size_t)iv[2] * D2C + c4);
  u16x4 o;
#pragma unroll
  for (int j = 0; j < 4; ++j) o[j] = f2b(wv[0] * a[j] + wv[1] * c[j] + wv[2] * e[j]);
  *(u16x4*)(X0 + (size_t)p * C0K + D1C + c4) = o;
}

// ---------------- fused GEMM: C = A[M][K]*Bw[256][K]^T + bias, + BN stats from acc ----------------
// 64-row x 256-col tiles, 4 waves (each 64r x 64c), XOR chunk-swizzled LDS.
// NORMA: apply y=relu(a*sc+sh) to A during staging (register path).
// TRANSP: write C as [B][256][8192] else row-major [M][256].
template <int KDIM, bool NORMA, bool TRANSP>
__global__ __launch_bounds__(256) void k_gemm_f(const unsigned short* __restrict__ A,
                                                const unsigned short* __restrict__ Bw,
                                                const float* __restrict__ bias,
                                                const f32x2* __restrict__ P,
                                                unsigned short* __restrict__ C,
                                                float* __restrict__ sums,
                                                float* __restrict__ ssq) {
  __shared__ unsigned short As[64 * 64];   // 8 KB
  __shared__ unsigned short Ws[256 * 64];  // 32 KB
  const int t = threadIdx.x;
  const int lane = t & 63, wid = t >> 6;  // wid == wave's column group (wc)
  const int m0 = blockIdx.x * 64;
  const int srow = t >> 3;     // 0..31 staging row-in-round
  const int schunk = t & 7;    // staging chunk slot
  const int slc = schunk ^ (srow & 7);  // logical k-chunk this thread stages (swizzle)
  f32x4 acc[4][4] = {};
  for (int k0 = 0; k0 < KDIM; k0 += 64) {
    __syncthreads();  // prior LDS reads done
    // ---- stage W tile [256][64] via global_load_lds, source-swizzled ----
#pragma unroll
    for (int i = 0; i < 8; ++i) {
      const unsigned short* src = Bw + (size_t)(i * 32 + srow) * KDIM + k0 + slc * 8;
      __builtin_amdgcn_global_load_lds((const __attribute__((address_space(1))) void*)src,
                                       (__attribute__((address_space(3))) void*)&Ws[(i * 32 + wid * 8) * 64],
                                       16, 0, 0);
    }
    // ---- stage A tile [64][64] ----
    if constexpr (NORMA) {
#pragma unroll
      for (int i = 0; i < 2; ++i) {
        const int m = i * 32 + srow;
        s16x8 v = *(const s16x8*)(A + (size_t)(m0 + m) * KDIM + k0 + slc * 8);
        s16x8 o;
#pragma unroll
        for (int j = 0; j < 8; ++j) {
          f32x2 pp = P[k0 + slc * 8 + j];
          o[j] = (short)f2b(fmaxf(fmaf(b2f((unsigned short)v[j]), pp[0], pp[1]), 0.f));
        }
        *(s16x8*)&As[m * 64 + schunk * 8] = o;  // phys chunk = schunk (= slc ^ (m&7))
      }
    } else {
#pragma unroll
      for (int i = 0; i < 2; ++i) {
        const unsigned short* src = A + (size_t)(m0 + i * 32 + srow) * KDIM + k0 + slc * 8;
        __builtin_amdgcn_global_load_lds((const __attribute__((address_space(1))) void*)src,
                                         (__attribute__((address_space(3))) void*)&As[(i * 32 + wid * 8) * 64],
                                         16, 0, 0);
      }
    }
    asm volatile("s_waitcnt vmcnt(0)" ::: "memory");
    __syncthreads();
    // ---- MFMA ----
#pragma unroll
    for (int kk = 0; kk < 2; ++kk) {
      const int pch = ((kk * 4 + (lane >> 4)) ^ (lane & 7)) * 8;  // swizzled phys chunk offset
      s16x8 af[4], bf[4];
#pragma unroll
      for (int mi = 0; mi < 4; ++mi)
        af[mi] = *(const s16x8*)&As[(mi * 16 + (lane & 15)) * 64 + pch];
#pragma unroll
      for (int ni = 0; ni < 4; ++ni)
        bf[ni] = *(const s16x8*)&Ws[(wid * 64 + ni * 16 + (lane & 15)) * 64 + pch];
#pragma unroll
      for (int mi = 0; mi < 4; ++mi)
#pragma unroll
        for (int ni = 0; ni < 4; ++ni)
          acc[mi][ni] =
              __builtin_amdgcn_mfma_f32_16x16x32_bf16(af[mi], bf[ni], acc[mi][ni], 0, 0, 0);
    }
  }
  // ---- epilogue: bias, stats from acc, store ----
  const int cb = wid * 64 + (lane & 15);
  float bv[4], s1[4], s2[4];
#pragma unroll
  for (int ni = 0; ni < 4; ++ni) {
    bv[ni] = bias[cb + ni * 16];
    s1[ni] = 0.f;
    s2[ni] = 0.f;
  }
#pragma unroll
  for (int mi = 0; mi < 4; ++mi)
#pragma unroll
    for (int ni = 0; ni < 4; ++ni)
#pragma unroll
      for (int rj = 0; rj < 4; ++rj) {
        float y = acc[mi][ni][rj] + bv[ni];
        acc[mi][ni][rj] = y;
        s1[ni] += y;
        s2[ni] = fmaf(y, y, s2[ni]);
      }
#pragma unroll
  for (int ni = 0; ni < 4; ++ni) {
    s1[ni] += __shfl_xor(s1[ni], 16);
    s1[ni] += __shfl_xor(s1[ni], 32);
    s2[ni] += __shfl_xor(s2[ni], 16);
    s2[ni] += __shfl_xor(s2[ni], 32);
  }
  if (lane < 16) {
#pragma unroll
    for (int ni = 0; ni < 4; ++ni) {
      atomicAdd(&sums[cb + ni * 16], s1[ni]);
      atomicAdd(&ssq[cb + ni * 16], s2[ni]);
    }
  }
  if (!TRANSP) {
#pragma unroll
    for (int mi = 0; mi < 4; ++mi) {
      const size_t rbase = m0 + mi * 16 + (lane >> 4) * 4;
#pragma unroll
      for (int ni = 0; ni < 4; ++ni) {
        const int cg = cb + ni * 16;
#pragma unroll
        for (int rj = 0; rj < 4; ++rj) C[(rbase + rj) * 256 + cg] = f2b(acc[mi][ni][rj]);
      }
    }
  } else {
    const size_t bq = m0 >> 13;
    const int nb = (m0 & 8191) + (lane >> 4) * 4;
#pragma unroll
    for (int mi = 0; mi < 4; ++mi) {
#pragma unroll
      for (int ni = 0; ni < 4; ++ni) {
        const int cg = cb + ni * 16;
        u16x4 v;
#pragma unroll
        for (int rj = 0; rj < 4; ++rj) v[rj] = f2b(acc[mi][ni][rj]);
        *(u16x4*)(C + ((bq * 256 + cg) << 13) + nb + mi * 16) = v;
      }
    }
  }
}

// ---------------- fold stats + gamma/beta -> per-channel scale/shift ----------------
__global__ void k_params(const float* __restrict__ sums, const float* __restrict__ ssq,
                         const float* __restrict__ gamma, const float* __restrict__ beta,
                         f32x2* __restrict__ P) {
  int c = threadIdx.x;
  float mean = sums[c] * (1.f / 65536.f);
  float var = ssq[c] * (1.f / 65536.f) - mean * mean;
  float sc = gamma[c] * rsqrtf(var + 1e-5f);
  f32x2 pp;
  pp[0] = sc;
  pp[1] = beta[c] - mean * sc;
  P[c] = pp;
}

// ---------------- normalize+relu -> fp32 out (already [B][256][N]) ----------------
__global__ __launch_bounds__(256) void k_final(const unsigned short* __restrict__ Yt,
                                               const f32x2* __restrict__ P,
                                               float* __restrict__ out) {
  const size_t i4 = ((size_t)blockIdx.x * 256 + threadIdx.x) * 4;
  const int c = (int)((i4 >> 13) & 255);
  const f32x2 p = P[c];
  u16x4 y = *(const u16x4*)(Yt + i4);
  f32x4 o;
#pragma unroll
  for (int j = 0; j < 4; ++j) o[j] = fmaxf(fmaf(b2f(y[j]), p[0], p[1]), 0.f);
  *(f32x4*)(out + i4) = o;
}

extern "C" void kernel_launch(void* const* d_in, const int* in_sizes, int n_in,
                              void* d_out, int out_size, void* d_ws, size_t ws_size,
                              hipStream_t stream) {
  const float* xyz1 = (const float*)d_in[0];
  const float* xyz2 = (const float*)d_in[1];
  const float* pts1 = (const float*)d_in[2];
  const float* pts2 = (const float*)d_in[3];
  const float* W0 = (const float*)d_in[4];
  const float* b0 = (const float*)d_in[5];
  const float* g0 = (const float*)d_in[6];
  const float* be0 = (const float*)d_in[7];
  const float* W1 = (const float*)d_in[8];
  const float* b1 = (const float*)d_in[9];
  const float* g1 = (const float*)d_in[10];
  const float* be1 = (const float*)d_in[11];
  float* out = (float*)d_out;
  char* ws = (char*)d_ws;

  // workspace layout (aliased; peak ~94.7 MB):
  float* f2t = (float*)(ws + 0);                          // 16 MB, live tr_f2t..interp
  int* idxb = (int*)(ws + 16777216);                      // 1 MB,  live merge..interp
  float* wb = (float*)(ws + 17825792);                    // 1 MB,  live merge..interp
  unsigned short* X0 = (unsigned short*)(ws + 18874368);  // 40 MB, live tr_x0..gemm0
  unsigned short* Yt = (unsigned short*)(ws + 18874368);  // 32 MB, live gemm1..final (aliases X0)
  unsigned short* Y0 = (unsigned short*)(ws + 60817408);  // 32 MB, live gemm0..gemm1
  f32x4* pd = (f32x4*)(ws + 60817408);                    // 16 MB, live dist..merge (aliases Y0)
  i32x4* pi = (i32x4*)(ws + 77594624);                    // 16 MB, live dist..merge
  unsigned short* W0b = (unsigned short*)(ws + 94371840);
  unsigned short* W1b = (unsigned short*)(ws + 94535680);
  float* sums0 = (float*)(ws + 94666752);
  float* ssq0 = sums0 + 256;
  float* sums1 = sums0 + 512;
  float* ssq1 = sums0 + 768;
  f32x2* P0 = (f32x2*)(ws + 94670848);
  f32x2* P1 = (f32x2*)(ws + 94672896);

  hipMemsetAsync(sums0, 0, 4096, stream);
  k_castw<<<80, 256, 0, stream>>>(W0, W0b, 81920);
  k_castw<<<64, 256, 0, stream>>>(W1, W1b, 65536);
  k_tr_f2t<<<dim3(32, 4, BB), 256, 0, stream>>>(pts2, f2t);
  k_dist<<<dim3(8, SCHUNKS, BB), 256, 0, stream>>>(xyz1, xyz2, pd, pi);
  k_merge<<<256, 256, 0, stream>>>(pd, pi, idxb, wb);
  k_tr_x0<<<dim3(128, BB), 256, 0, stream>>>(pts1, X0);
  k_interp<<<16384, 256, 0, stream>>>(f2t, idxb, wb, X0);
  k_gemm_f<320, false, false><<<1024, 256, 0, stream>>>(X0, W0b, b0, nullptr, Y0, sums0, ssq0);
  k_params<<<1, 256, 0, stream>>>(sums0, ssq0, g0, be0, P0);
  k_gemm_f<256, true, true><<<1024, 256, 0, stream>>>(Y0, W1b, b1, P0, Yt, sums1, ssq1);
  k_params<<<1, 256, 0, stream>>>(sums1, ssq1, g1, be1, P1);
  k_final<<<16384, 256, 0, stream>>>(Yt, P1, out);
}